// Round 4
// baseline (151.326 us; speedup 1.0000x reference)
//
#include <hip/hip_runtime.h>

namespace {

constexpr int kNXI = 33;                    // x rows tracked: 0..16, 112..127
constexpr int kNY = 16;                     // y modes 0..15
constexpr int kNMODE = kNY * kNXI;          // 528 slots (497 active)

// ws float offsets
constexpr int WS_ALPHA = 0;
constexpr int WS_GAMMA = 1;
constexpr int WS_S = 4;                                 // s[528] complex
constexpr int WS_ZY = WS_S + kNMODE * 2;                // Zy[16][128][16] complex
constexpr int WS_T = WS_ZY;                             // T aliases Zy

constexpr float kTheta = 0.04908738521234052f;          // 2*pi/128

__device__ __forceinline__ float wave_sum(float v) {
  v += __shfl_xor(v, 1);  v += __shfl_xor(v, 2);  v += __shfl_xor(v, 4);
  v += __shfl_xor(v, 8);  v += __shfl_xor(v, 16); v += __shfl_xor(v, 32);
  return v;
}

// ---------------- per-mode RK4 evolution: 1 wave per mode, W in VGPRs ----------------
// Lane o owns output channel o: W column o in registers (Wc[64] float2 = 128 VGPR),
// state broadcast from a 512B LDS buffer. No cross-lane reduction in the matvec.
__global__ __launch_bounds__(64, 1) void fnde_modes(
    const float* __restrict__ w1, const float* __restrict__ w2,
    const float* __restrict__ flb, const float* __restrict__ lw,
    const float* __restrict__ lb, const float* __restrict__ ts,
    const float* __restrict__ p1w, const float* __restrict__ p1b,
    const float* __restrict__ p2w, const float* __restrict__ p2b,
    float* __restrict__ ws) {
  const int o = threadIdx.x;                 // lane 0..63
  const int wgd = blockIdx.x;

  __shared__ float2 xb[64];

  const float t0 = ts[0], t1 = ts[1], t2 = ts[2], t3 = ts[3], t4 = ts[4];
  const float h0 = t1 - t0, h1 = t2 - t1, h2 = t3 - t2, h3 = t4 - t3;

  // q[o] = (p2*p1)[o]
  float q = 0.f;
  for (int p = 0; p < 64; ++p) q = fmaf(p2w[p], p1w[p * 64 + o], q);

  if (wgd == kNMODE) {
    // ---- bias-response chain: real arithmetic; W = Re(w1[.,.,0,0]) ----
    const float* lanep = w1 + o * 512;       // (i stride = 64*512 floats)
    float e = lb[o];
    xb[o].x = e;
    __syncthreads();
    float Wc[64];
    for (int l = 0; l < 3; ++l) {
#pragma unroll
      for (int i = 0; i < 64; ++i) Wc[i] = lanep[(l * 64 + i) * 32768];
      const float b = flb[l * 64 + o];
      for (int step = 0; step < 4; ++step) {
        const float h = (step == 0) ? h0 : (step == 1) ? h1 : (step == 2) ? h2 : h3;
        float acc = 0.f;
        for (int st = 0; st < 4; ++st) {
          float k0 = 0.f, k1a = 0.f;
#pragma unroll
          for (int i = 0; i < 64; i += 2) {
            k0  = fmaf(Wc[i],     xb[i].x,     k0);
            k1a = fmaf(Wc[i + 1], xb[i + 1].x, k1a);
          }
          const float k = k0 + k1a + b;
          const float wsm = (st == 1 || st == 2) ? 2.f : 1.f;
          acc = fmaf(wsm, k, acc);
          float u;
          if (st < 3) { const float cm = (st < 2) ? 0.5f * h : h; u = fmaf(cm, k, e); }
          else        { e = fmaf(h * (1.f / 6.f), acc, e); u = e; }
          __syncthreads();
          xb[o].x = u;
          __syncthreads();
        }
      }
    }
    const float g = wave_sum(fmaf(p2w[o], p1b[o], q * e));
    if (o == 0) ws[WS_GAMMA] = g + p2b[0];
    return;
  }

  // XCD-affinity mapping: the 16 y-modes of one xi-column share an XCD
  const int xcd = wgd & 7, kk0 = wgd >> 3;
  int xi, y;
  if (kk0 < 64) { xi = xcd * 4 + (kk0 >> 4); y = kk0 & 15; }
  else          { xi = 32;                   y = xcd * 2 + (kk0 - 64); }
  const int m = y * kNXI + xi;

  const bool inactive = (y == 0) ? (xi > 16) : (xi == 16);
  if (inactive) {
    if (o == 0) { ws[WS_S + 2 * m] = 0.f; ws[WS_S + 2 * m + 1] = 0.f; }
    return;
  }

  float zr = lw[o], zi = 0.f;
  xb[o] = make_float2(zr, zi);
  __syncthreads();

  float2 Wc[64];

  auto rk4_layer = [&]() {
    for (int step = 0; step < 4; ++step) {
      const float h = (step == 0) ? h0 : (step == 1) ? h1 : (step == 2) ? h2 : h3;
      float accr = 0.f, acci = 0.f;
      for (int st = 0; st < 4; ++st) {
        float ar0 = 0.f, ai0 = 0.f, ar1 = 0.f, ai1 = 0.f;
#pragma unroll
        for (int i = 0; i < 64; i += 2) {
          const float2 x0 = xb[i], x1 = xb[i + 1];
          const float2 w0 = Wc[i], w1v = Wc[i + 1];
          ar0 = fmaf(w0.x, x0.x, ar0);  ar0 = fmaf(-w0.y, x0.y, ar0);
          ai0 = fmaf(w0.x, x0.y, ai0);  ai0 = fmaf(w0.y, x0.x, ai0);
          ar1 = fmaf(w1v.x, x1.x, ar1); ar1 = fmaf(-w1v.y, x1.y, ar1);
          ai1 = fmaf(w1v.x, x1.y, ai1); ai1 = fmaf(w1v.y, x1.x, ai1);
        }
        const float kr = ar0 + ar1, ki = ai0 + ai1;
        const float wsm = (st == 1 || st == 2) ? 2.f : 1.f;
        accr = fmaf(wsm, kr, accr); acci = fmaf(wsm, ki, acci);
        float ur, ui;
        if (st < 3) {
          const float cm = (st < 2) ? 0.5f * h : h;
          ur = fmaf(cm, kr, zr); ui = fmaf(cm, ki, zi);
        } else {
          zr = fmaf(h * (1.f / 6.f), accr, zr);
          zi = fmaf(h * (1.f / 6.f), acci, zi);
          ur = zr; ui = zi;
        }
        __syncthreads();
        xb[o] = make_float2(ur, ui);
        __syncthreads();
      }
    }
  };

  if (y >= 1) {
    // single weight stream; double-buffered register prefetch
    const float* lanep = ((xi <= 15) ? (w1 + (xi * 16 + y) * 2)
                                     : (w2 + ((xi - 17) * 16 + y) * 2)) + o * 512;
    float2 Wn[64];
#pragma unroll
    for (int i = 0; i < 64; ++i)
      Wn[i] = *reinterpret_cast<const float2*>(lanep + i * 32768);
    for (int l = 0; l < 3; ++l) {
#pragma unroll
      for (int i = 0; i < 64; ++i) Wc[i] = Wn[i];
      if (l < 2) {
#pragma unroll
        for (int i = 0; i < 64; ++i)
          Wn[i] = *reinterpret_cast<const float2*>(lanep + ((l + 1) * 64 + i) * 32768);
      }
      rk4_layer();
    }
  } else {
    // y==0: Hermitian combine of two streams; load synchronously per layer
    const bool hasA = (xi <= 15);
    const float* lanepA = w1 + xi * 32 + o * 512;
    const float* lanepB = (xi >= 1) ? (w2 + (16 - xi) * 32 + o * 512)
                                    : (w1 + o * 512);
    for (int l = 0; l < 3; ++l) {
#pragma unroll
      for (int i = 0; i < 64; ++i) {
        const float2 a = hasA ? *reinterpret_cast<const float2*>(lanepA + (l * 64 + i) * 32768)
                              : make_float2(0.f, 0.f);
        const float2 bb = *reinterpret_cast<const float2*>(lanepB + (l * 64 + i) * 32768);
        Wc[i] = make_float2(0.5f * (a.x + bb.x), 0.5f * (a.y - bb.y));
      }
      rk4_layer();
    }
  }

  const float sr = wave_sum(q * (zr - lw[o]));
  const float si = wave_sum(q * zi);
  if (o == 0) { ws[WS_S + 2 * m] = sr; ws[WS_S + 2 * m + 1] = si; }
  if (y == 0 && xi == 0) {
    const float a = wave_sum(q * lw[o]);
    if (o == 0) ws[WS_ALPHA] = a;
  }
}

// ---------------- forward DFT stage 1: over ys ----------------
__global__ void fnde_fwd1(const float* __restrict__ z, float* __restrict__ ws) {
  const int bid = blockIdx.x;             // b*128 + xs
  const int b = bid >> 7, xs = bid & 127;
  const int t = threadIdx.x;              // 128
  __shared__ float zrow[128], tc[128], tsn[128], rre[128], rim[128];
  sincosf((float)t * kTheta, &tsn[t], &tc[t]);
  zrow[t] = z[b * 16384 + xs * 128 + t];
  __syncthreads();
  int y = t & 15, part = t >> 4;          // 8 partial groups
  float sre = 0.f, sim = 0.f;
  for (int j = 0; j < 16; ++j) {
    int ys = (part << 4) + j;
    int k = (y * ys) & 127;
    float zv = zrow[ys];
    sre += zv * tc[k];
    sim -= zv * tsn[k];
  }
  rre[t] = sre; rim[t] = sim;
  __syncthreads();
  if (t < 16) {
    float ar = 0.f, ai = 0.f;
    for (int pp = 0; pp < 8; ++pp) { ar += rre[(pp << 4) + t]; ai += rim[(pp << 4) + t]; }
    int idx = ((b * 128 + xs) * 16 + t) * 2;
    ws[WS_ZY + idx] = ar; ws[WS_ZY + idx + 1] = ai;
  }
}

// ---------------- fused: x-DFT at tracked rows, *S, inverse over xs ----------------
__global__ void fnde_mid(float* __restrict__ ws) {
  const int b = blockIdx.x >> 4, y = blockIdx.x & 15;
  const int t = threadIdx.x;              // 128
  __shared__ float cr[128], ci[128], tc[128], tsn[128], Sre[kNXI], Sim[kNXI];
  sincosf((float)t * kTheta, &tsn[t], &tc[t]);
  int idx = ((b * 128 + t) * 16 + y) * 2;
  cr[t] = ws[WS_ZY + idx]; ci[t] = ws[WS_ZY + idx + 1];
  __syncthreads();
  if (t < kNXI) {
    int x = (t <= 16) ? t : t + 95;
    float ar = 0.f, ai = 0.f;
    for (int xs = 0; xs < 128; ++xs) {
      int k = (x * xs) & 127;
      float c = tc[k], s = tsn[k];
      ar += cr[xs] * c + ci[xs] * s;
      ai += ci[xs] * c - cr[xs] * s;
    }
    int mm = y * kNXI + t;
    float sr = ws[WS_S + 2 * mm], si = ws[WS_S + 2 * mm + 1];
    Sre[t] = sr * ar - si * ai;
    Sim[t] = sr * ai + si * ar;
  }
  __syncthreads();
  const int xs = t;
  float ar, ai;
  if (y > 0) {
    ar = 0.f; ai = 0.f;
    for (int xj = 0; xj < kNXI; ++xj) {
      int x = (xj <= 16) ? xj : xj + 95;
      int k = (x * xs) & 127;
      float c = tc[k], s = tsn[k];
      ar += Sre[xj] * c - Sim[xj] * s;   // e^{+i}
      ai += Sre[xj] * s + Sim[xj] * c;
    }
  } else {
    ar = Sre[0]; ai = 0.f;               // x-col 0: Hermitian pairs -> real
    for (int xj = 1; xj <= 16; ++xj) {
      int k = (xj * xs) & 127;
      ar += 2.f * (Sre[xj] * tc[k] - Sim[xj] * tsn[k]);
    }
  }
  ws[WS_T + idx] = ar; ws[WS_T + idx + 1] = ai;   // in-place per (b,y) slice
}

// ---------------- inverse stage 2 + epilogue ----------------
__global__ void fnde_final(const float* __restrict__ z, const float* __restrict__ ws,
                           float* __restrict__ out) {
  const int bid = blockIdx.x;             // b*128 + xs
  const int b = bid >> 7, xs = bid & 127;
  const int t = threadIdx.x;              // 128 (ys)
  __shared__ float Tre[16], Tim[16], tc[128], tsn[128];
  sincosf((float)t * kTheta, &tsn[t], &tc[t]);
  if (t < 16) {
    int idx = ((b * 128 + xs) * 16 + t) * 2;
    Tre[t] = ws[WS_T + idx]; Tim[t] = ws[WS_T + idx + 1];
  }
  __syncthreads();
  float acc = Tre[0];
  for (int y = 1; y < 16; ++y) {
    int k = (y * t) & 127;
    acc += 2.f * (Tre[y] * tc[k] - Tim[y] * tsn[k]);   // 2*Re(T * e^{+i})
  }
  float val = ws[WS_ALPHA] * z[b * 16384 + xs * 128 + t] + ws[WS_GAMMA]
            + acc * (1.f / 16384.f);
  out[b * 16384 + xs * 128 + t] = val;
}

}  // namespace

extern "C" void kernel_launch(void* const* d_in, const int* in_sizes, int n_in,
                              void* d_out, int out_size, void* d_ws, size_t ws_size,
                              hipStream_t stream) {
  (void)in_sizes; (void)n_in; (void)out_size; (void)ws_size;
  const float* z   = (const float*)d_in[0];
  const float* lw  = (const float*)d_in[1];
  const float* lb  = (const float*)d_in[2];
  const float* w1  = (const float*)d_in[3];
  const float* w2  = (const float*)d_in[4];
  const float* flb = (const float*)d_in[5];
  const float* p1w = (const float*)d_in[6];
  const float* p1b = (const float*)d_in[7];
  const float* p2w = (const float*)d_in[8];
  const float* p2b = (const float*)d_in[9];
  const float* ts  = (const float*)d_in[10];
  float* ws = (float*)d_ws;
  float* out = (float*)d_out;

  fnde_modes<<<dim3(kNMODE + 1), dim3(64), 0, stream>>>(w1, w2, flb, lw, lb, ts,
                                                        p1w, p1b, p2w, p2b, ws);
  fnde_fwd1<<<dim3(2048), dim3(128), 0, stream>>>(z, ws);
  fnde_mid<<<dim3(256), dim3(128), 0, stream>>>(ws);
  fnde_final<<<dim3(2048), dim3(128), 0, stream>>>(z, ws, out);
}

// Round 5
// 94.575 us; speedup vs baseline: 1.6001x; 1.6001x over previous
//
#include <hip/hip_runtime.h>

namespace {

constexpr int kNXI = 33;                    // x rows tracked: 0..16, 112..127
constexpr int kNY = 16;                     // y modes 0..15
constexpr int kNMODE = kNY * kNXI;          // 528 slots (497 active)
constexpr int kModeBlocks = 265;            // 264 dual-mode blocks + 1 bias block
constexpr int kFwd1Blocks = 2048;

// ws float offsets
constexpr int WS_ALPHA = 0;
constexpr int WS_GAMMA = 1;
constexpr int WS_S = 4;                                 // s[528] complex
constexpr int WS_ZY = WS_S + kNMODE * 2;                // Zy[16][128][16] complex
constexpr int WS_T = WS_ZY;                             // T aliases Zy

constexpr float kTheta = 0.04908738521234052f;          // 2*pi/128

__device__ __forceinline__ float rl(float v, int i) {
  return __uint_as_float(__builtin_amdgcn_readlane(__float_as_uint(v), i));
}

__device__ __forceinline__ float wave_sum(float v) {
  v += __shfl_xor(v, 1);  v += __shfl_xor(v, 2);  v += __shfl_xor(v, 4);
  v += __shfl_xor(v, 8);  v += __shfl_xor(v, 16); v += __shfl_xor(v, 32);
  return v;
}

// ---------------- phase1: per-mode RK4 (barrier-free, readlane broadcast) + fwd1 ----------------
// Mode wave: lane o owns output channel o; W column o in VGPRs (Wc[64] float2);
// state broadcast lane->all via v_readlane. No LDS, no barriers in the chain.
__global__ __launch_bounds__(128) void fnde_phase1(
    const float* __restrict__ w1, const float* __restrict__ w2,
    const float* __restrict__ flb, const float* __restrict__ lw,
    const float* __restrict__ lb, const float* __restrict__ ts,
    const float* __restrict__ p1w, const float* __restrict__ p1b,
    const float* __restrict__ p2w, const float* __restrict__ p2b,
    const float* __restrict__ z, float* __restrict__ ws) {
  const int b = blockIdx.x;

  if (b >= kModeBlocks) {
    // ---------------- fwd1: forward DFT over ys ----------------
    const int bid = b - kModeBlocks;      // b*128 + xs
    const int bb = bid >> 7, xs = bid & 127;
    const int t = threadIdx.x;            // 128
    __shared__ float zrow[128], tc[128], tsn[128], rre[128], rim[128];
    sincosf((float)t * kTheta, &tsn[t], &tc[t]);
    zrow[t] = z[bb * 16384 + xs * 128 + t];
    __syncthreads();
    int y = t & 15, part = t >> 4;        // 8 partial groups
    float sre = 0.f, sim = 0.f;
    for (int j = 0; j < 16; ++j) {
      int ys = (part << 4) + j;
      int k = (y * ys) & 127;
      float zv = zrow[ys];
      sre += zv * tc[k];
      sim -= zv * tsn[k];
    }
    rre[t] = sre; rim[t] = sim;
    __syncthreads();
    if (t < 16) {
      float ar = 0.f, ai = 0.f;
      for (int pp = 0; pp < 8; ++pp) { ar += rre[(pp << 4) + t]; ai += rim[(pp << 4) + t]; }
      int idx = ((bb * 128 + xs) * 16 + t) * 2;
      ws[WS_ZY + idx] = ar; ws[WS_ZY + idx + 1] = ai;
    }
    return;
  }

  const int t = threadIdx.x;
  const int o = t & 63, w = t >> 6;       // two independent waves per block

  const float t0 = ts[0], t1 = ts[1], t2 = ts[2], t3 = ts[3], t4 = ts[4];
  const float h0 = t1 - t0, h1 = t2 - t1, h2 = t3 - t2, h3 = t4 - t3;

  if (b == kModeBlocks - 1) {
    // ---------------- bias-response chain (real arithmetic), wave 0 only ----------------
    if (w == 1) return;
    float q = 0.f;
    for (int p = 0; p < 64; ++p) q = fmaf(p2w[p], p1w[p * 64 + o], q);
    float e = lb[o];
    const float* lanep = w1 + o * 512;
    for (int l = 0; l < 3; ++l) {
      float Wc[64];
#pragma unroll
      for (int i = 0; i < 64; ++i) Wc[i] = lanep[(size_t)(l * 64 + i) * 32768];
      const float bia = flb[l * 64 + o];
      for (int step = 0; step < 4; ++step) {
        const float h = (step == 0) ? h0 : (step == 1) ? h1 : (step == 2) ? h2 : h3;
        float acc = 0.f, u = e;
        for (int st = 0; st < 4; ++st) {
          float k0 = 0.f, k1 = 0.f;
#pragma unroll
          for (int i = 0; i < 64; i += 2) {
            k0 = fmaf(Wc[i],     rl(u, i),     k0);
            k1 = fmaf(Wc[i + 1], rl(u, i + 1), k1);
          }
          const float k = k0 + k1 + bia;
          const float wsm = (st == 1 || st == 2) ? 2.f : 1.f;
          acc = fmaf(wsm, k, acc);
          if (st < 3) {
            const float cm = (st < 2) ? 0.5f * h : h;
            u = fmaf(cm, k, e);
          } else {
            e = fmaf(h * (1.f / 6.f), acc, e);
          }
        }
      }
    }
    const float g = wave_sum(fmaf(p2w[o], p1b[o], q * e));
    if (o == 0) ws[WS_GAMMA] = g + p2b[0];
    return;
  }

  // ---------------- mode waves: XCD-affinity mapping ----------------
  const int xcd = b & 7, kk0 = (b >> 3) * 2 + w;   // b in [0,263], kk0 in [0,65]
  int xi, y;
  if (kk0 < 64) { xi = xcd * 4 + (kk0 >> 4); y = kk0 & 15; }
  else          { xi = 32;                   y = xcd * 2 + (kk0 - 64); }
  const int m = y * kNXI + xi;

  const bool inactive = (y == 0) ? (xi > 16) : (xi == 16);
  if (inactive) {
    if (o == 0) { ws[WS_S + 2 * m] = 0.f; ws[WS_S + 2 * m + 1] = 0.f; }
    return;
  }

  float q = 0.f;
  for (int p = 0; p < 64; ++p) q = fmaf(p2w[p], p1w[p * 64 + o], q);

  float zr = lw[o], zi = 0.f;
  float2 Wc[64];

  for (int l = 0; l < 3; ++l) {
    if (y >= 1) {
      const float* lanep = ((xi <= 15) ? (w1 + (xi * 16 + y) * 2)
                                       : (w2 + ((xi - 17) * 16 + y) * 2)) + o * 512;
#pragma unroll
      for (int i = 0; i < 64; ++i)
        Wc[i] = *reinterpret_cast<const float2*>(lanep + (size_t)(l * 64 + i) * 32768);
    } else {
      // y==0: Hermitian combine of w1 and conj(w2 partner)
      const bool hasA = (xi <= 15);
      const float* lanepA = w1 + xi * 32 + o * 512;
      const float* lanepB = (xi >= 1) ? (w2 + (16 - xi) * 32 + o * 512)
                                      : (w1 + o * 512);
#pragma unroll
      for (int i = 0; i < 64; ++i) {
        const float2 a = hasA ? *reinterpret_cast<const float2*>(lanepA + (size_t)(l * 64 + i) * 32768)
                              : make_float2(0.f, 0.f);
        const float2 bb = *reinterpret_cast<const float2*>(lanepB + (size_t)(l * 64 + i) * 32768);
        Wc[i] = make_float2(0.5f * (a.x + bb.x), 0.5f * (a.y - bb.y));
      }
    }

    for (int step = 0; step < 4; ++step) {
      const float h = (step == 0) ? h0 : (step == 1) ? h1 : (step == 2) ? h2 : h3;
      float accr = 0.f, acci = 0.f;
      float ur = zr, ui = zi;
      for (int st = 0; st < 4; ++st) {
        float ar0 = 0.f, ai0 = 0.f, ar1 = 0.f, ai1 = 0.f;
#pragma unroll
        for (int i = 0; i < 64; i += 2) {
          const float x0r = rl(ur, i),     x0i = rl(ui, i);
          const float x1r = rl(ur, i + 1), x1i = rl(ui, i + 1);
          ar0 = fmaf(Wc[i].x,     x0r, ar0);  ar0 = fmaf(-Wc[i].y,     x0i, ar0);
          ai0 = fmaf(Wc[i].x,     x0i, ai0);  ai0 = fmaf(Wc[i].y,     x0r, ai0);
          ar1 = fmaf(Wc[i + 1].x, x1r, ar1);  ar1 = fmaf(-Wc[i + 1].y, x1i, ar1);
          ai1 = fmaf(Wc[i + 1].x, x1i, ai1);  ai1 = fmaf(Wc[i + 1].y,  x1r, ai1);
        }
        const float kr = ar0 + ar1, ki = ai0 + ai1;
        const float wsm = (st == 1 || st == 2) ? 2.f : 1.f;
        accr = fmaf(wsm, kr, accr); acci = fmaf(wsm, ki, acci);
        if (st < 3) {
          const float cm = (st < 2) ? 0.5f * h : h;
          ur = fmaf(cm, kr, zr); ui = fmaf(cm, ki, zi);
        } else {
          zr = fmaf(h * (1.f / 6.f), accr, zr);
          zi = fmaf(h * (1.f / 6.f), acci, zi);
        }
      }
    }
  }

  const float sr = wave_sum(q * (zr - lw[o]));
  const float si = wave_sum(q * zi);
  if (o == 0) { ws[WS_S + 2 * m] = sr; ws[WS_S + 2 * m + 1] = si; }
  if (y == 0 && xi == 0) {
    const float a = wave_sum(q * lw[o]);
    if (o == 0) ws[WS_ALPHA] = a;
  }
}

// ---------------- fused: x-DFT at tracked rows, *S, inverse over xs ----------------
__global__ void fnde_mid(float* __restrict__ ws) {
  const int b = blockIdx.x >> 4, y = blockIdx.x & 15;
  const int t = threadIdx.x;              // 128
  __shared__ float cr[128], ci[128], tc[128], tsn[128], Sre[kNXI], Sim[kNXI];
  sincosf((float)t * kTheta, &tsn[t], &tc[t]);
  int idx = ((b * 128 + t) * 16 + y) * 2;
  cr[t] = ws[WS_ZY + idx]; ci[t] = ws[WS_ZY + idx + 1];
  __syncthreads();
  if (t < kNXI) {
    int x = (t <= 16) ? t : t + 95;
    float ar = 0.f, ai = 0.f;
    for (int xs = 0; xs < 128; ++xs) {
      int k = (x * xs) & 127;
      float c = tc[k], s = tsn[k];
      ar += cr[xs] * c + ci[xs] * s;
      ai += ci[xs] * c - cr[xs] * s;
    }
    int mm = y * kNXI + t;
    float sr = ws[WS_S + 2 * mm], si = ws[WS_S + 2 * mm + 1];
    Sre[t] = sr * ar - si * ai;
    Sim[t] = sr * ai + si * ar;
  }
  __syncthreads();
  const int xs = t;
  float ar, ai;
  if (y > 0) {
    ar = 0.f; ai = 0.f;
    for (int xj = 0; xj < kNXI; ++xj) {
      int x = (xj <= 16) ? xj : xj + 95;
      int k = (x * xs) & 127;
      float c = tc[k], s = tsn[k];
      ar += Sre[xj] * c - Sim[xj] * s;   // e^{+i}
      ai += Sre[xj] * s + Sim[xj] * c;
    }
  } else {
    ar = Sre[0]; ai = 0.f;               // x-col 0: Hermitian pairs -> real
    for (int xj = 1; xj <= 16; ++xj) {
      int k = (xj * xs) & 127;
      ar += 2.f * (Sre[xj] * tc[k] - Sim[xj] * tsn[k]);
    }
  }
  ws[WS_T + idx] = ar; ws[WS_T + idx + 1] = ai;   // in-place per (b,y) slice
}

// ---------------- inverse stage 2 + epilogue ----------------
__global__ void fnde_final(const float* __restrict__ z, const float* __restrict__ ws,
                           float* __restrict__ out) {
  const int bid = blockIdx.x;             // b*128 + xs
  const int b = bid >> 7, xs = bid & 127;
  const int t = threadIdx.x;              // 128 (ys)
  __shared__ float Tre[16], Tim[16], tc[128], tsn[128];
  sincosf((float)t * kTheta, &tsn[t], &tc[t]);
  if (t < 16) {
    int idx = ((b * 128 + xs) * 16 + t) * 2;
    Tre[t] = ws[WS_T + idx]; Tim[t] = ws[WS_T + idx + 1];
  }
  __syncthreads();
  float acc = Tre[0];
  for (int y = 1; y < 16; ++y) {
    int k = (y * t) & 127;
    acc += 2.f * (Tre[y] * tc[k] - Tim[y] * tsn[k]);   // 2*Re(T * e^{+i})
  }
  float val = ws[WS_ALPHA] * z[b * 16384 + xs * 128 + t] + ws[WS_GAMMA]
            + acc * (1.f / 16384.f);
  out[b * 16384 + xs * 128 + t] = val;
}

}  // namespace

extern "C" void kernel_launch(void* const* d_in, const int* in_sizes, int n_in,
                              void* d_out, int out_size, void* d_ws, size_t ws_size,
                              hipStream_t stream) {
  (void)in_sizes; (void)n_in; (void)out_size; (void)ws_size;
  const float* z   = (const float*)d_in[0];
  const float* lw  = (const float*)d_in[1];
  const float* lb  = (const float*)d_in[2];
  const float* w1  = (const float*)d_in[3];
  const float* w2  = (const float*)d_in[4];
  const float* flb = (const float*)d_in[5];
  const float* p1w = (const float*)d_in[6];
  const float* p1b = (const float*)d_in[7];
  const float* p2w = (const float*)d_in[8];
  const float* p2b = (const float*)d_in[9];
  const float* ts  = (const float*)d_in[10];
  float* ws = (float*)d_ws;
  float* out = (float*)d_out;

  fnde_phase1<<<dim3(kModeBlocks + kFwd1Blocks), dim3(128), 0, stream>>>(
      w1, w2, flb, lw, lb, ts, p1w, p1b, p2w, p2b, z, ws);
  fnde_mid<<<dim3(256), dim3(128), 0, stream>>>(ws);
  fnde_final<<<dim3(2048), dim3(128), 0, stream>>>(z, ws, out);
}

// Round 6
// 94.482 us; speedup vs baseline: 1.6016x; 1.0010x over previous
//
#include <hip/hip_runtime.h>

namespace {

constexpr int kNXI = 33;                    // x rows tracked: 0..16, 112..127
constexpr int kNY = 16;                     // y modes 0..15
constexpr int kNMODE = kNY * kNXI;          // 528 slots (497 active)
constexpr int kModeBlocks = 529;            // 528 mode slots + 1 bias block
constexpr int kFwd1Blocks = 1024;           // 2 rows per block

// ws float offsets
constexpr int WS_ALPHA = 0;
constexpr int WS_GAMMA = 1;
constexpr int WS_S = 4;                                 // s[528] complex
constexpr int WS_ZY = WS_S + kNMODE * 2;                // Zy[16][128][16] complex
constexpr int WS_T = WS_ZY;                             // T aliases Zy

constexpr float kTheta = 0.04908738521234052f;          // 2*pi/128

__device__ __forceinline__ float wave_sum(float v) {
  v += __shfl_xor(v, 1);  v += __shfl_xor(v, 2);  v += __shfl_xor(v, 4);
  v += __shfl_xor(v, 8);  v += __shfl_xor(v, 16); v += __shfl_xor(v, 32);
  return v;
}

// ---------------- phase1: per-mode RK4 (4 waves/mode, i-split) + fwd1 ----------------
// Wave w owns i in [16w,16w+16): W-slice in 32 VGPR. Every wave redundantly keeps
// the full state u[o] in lane o; reads its OWN LDS state copy (no barrier needed),
// exchanges 16-term partials via double-buffered LDS with ONE barrier per stage.
__global__ __launch_bounds__(256) void fnde_phase1(
    const float* __restrict__ w1, const float* __restrict__ w2,
    const float* __restrict__ flb, const float* __restrict__ lw,
    const float* __restrict__ lb, const float* __restrict__ ts,
    const float* __restrict__ p1w, const float* __restrict__ p1b,
    const float* __restrict__ p2w, const float* __restrict__ p2b,
    const float* __restrict__ z, float* __restrict__ ws) {
  const int b = blockIdx.x;
  const int t = threadIdx.x;

  if (b >= kModeBlocks) {
    // ---------------- fwd1: forward DFT over ys (2 rows per block) ----------------
    __shared__ float zrow2[2][128], tcf[128], tsnf[128], rre2[2][128], rim2[2][128];
    const int bid = b - kModeBlocks;
    const int r = t >> 7, tt = t & 127;
    const int row = bid * 2 + r;          // row = bb*128 + xs
    const int bb = row >> 7, xs = row & 127;
    if (r == 0) sincosf((float)tt * kTheta, &tsnf[tt], &tcf[tt]);
    zrow2[r][tt] = z[bb * 16384 + xs * 128 + tt];
    __syncthreads();
    int y = tt & 15, part = tt >> 4;      // 8 partial groups
    float sre = 0.f, sim = 0.f;
    for (int j = 0; j < 16; ++j) {
      int ys = (part << 4) + j;
      int k = (y * ys) & 127;
      float zv = zrow2[r][ys];
      sre += zv * tcf[k];
      sim -= zv * tsnf[k];
    }
    rre2[r][tt] = sre; rim2[r][tt] = sim;
    __syncthreads();
    if (tt < 16) {
      float ar = 0.f, ai = 0.f;
      for (int pp = 0; pp < 8; ++pp) { ar += rre2[r][(pp << 4) + tt]; ai += rim2[r][(pp << 4) + tt]; }
      int idx = (row * 16 + tt) * 2;
      ws[WS_ZY + idx] = ar; ws[WS_ZY + idx + 1] = ai;
    }
    return;
  }

  // ---------------- mode / bias blocks ----------------
  const int w = t >> 6, o = t & 63;
  const bool isBias = (b == kModeBlocks - 1);

  int xi = 0, y = 0, m = 0;
  if (!isBias) {
    const int xcd = b & 7, k = b >> 3;     // XCD affinity: 16 y's of one xi share an XCD
    if (k < 64) { xi = xcd * 4 + (k >> 4); y = k & 15; }
    else        { xi = 32;                 y = xcd * 2 + (k - 64); }
    m = y * kNXI + xi;
    const bool inactive = (y == 0) ? (xi > 16) : (xi == 16);
    if (inactive) {
      if (t == 0) { ws[WS_S + 2 * m] = 0.f; ws[WS_S + 2 * m + 1] = 0.f; }
      return;
    }
  }

  __shared__ float2 ubuf[4][64];          // per-wave full-state copies
  __shared__ float2 pbuf[2][4][64];       // double-buffered partials

  const float t0 = ts[0], t1 = ts[1], t2 = ts[2], t3 = ts[3], t4 = ts[4];
  const float h0 = t1 - t0, h1 = t2 - t1, h2 = t3 - t2, h3 = t4 - t3;

  float q = 0.f;
  if (w == 0) {
    for (int p = 0; p < 64; ++p) q = fmaf(p2w[p], p1w[p * 64 + o], q);
  }

  float zr = isBias ? lb[o] : lw[o], zi = 0.f;
  ubuf[w][o] = make_float2(zr, zi);       // own-wave write; first read below (lgkm only)

  int pb = 0;
  float2 Wc[16];

  for (int l = 0; l < 3; ++l) {
    // ---- load W slice: Wc[j] = W[16w+j][o] ----
    if (isBias) {
      const float* lanep = w1 + o * 512;
#pragma unroll
      for (int j = 0; j < 16; ++j)
        Wc[j] = make_float2(lanep[(size_t)(l * 64 + 16 * w + j) * 32768], 0.f);
    } else if (y >= 1) {
      const float* lanep = ((xi <= 15) ? (w1 + (xi * 16 + y) * 2)
                                       : (w2 + ((xi - 17) * 16 + y) * 2)) + o * 512;
#pragma unroll
      for (int j = 0; j < 16; ++j)
        Wc[j] = *reinterpret_cast<const float2*>(lanep + (size_t)(l * 64 + 16 * w + j) * 32768);
    } else {
      // y==0: Hermitian combine of w1 and conj(w2 partner)
      const bool hasA = (xi <= 15);
      const float* lanepA = w1 + xi * 32 + o * 512;
      const float* lanepB = (xi >= 1) ? (w2 + (16 - xi) * 32 + o * 512)
                                      : (w1 + o * 512);
#pragma unroll
      for (int j = 0; j < 16; ++j) {
        const size_t ioff = (size_t)(l * 64 + 16 * w + j) * 32768;
        const float2 a = hasA ? *reinterpret_cast<const float2*>(lanepA + ioff)
                              : make_float2(0.f, 0.f);
        const float2 bb2 = *reinterpret_cast<const float2*>(lanepB + ioff);
        Wc[j] = make_float2(0.5f * (a.x + bb2.x), 0.5f * (a.y - bb2.y));
      }
    }
    const float bia = isBias ? flb[l * 64 + o] : 0.f;

    for (int step = 0; step < 4; ++step) {
      const float h = (step == 0) ? h0 : (step == 1) ? h1 : (step == 2) ? h2 : h3;
      float accr = 0.f, acci = 0.f;
      for (int st = 0; st < 4; ++st) {
        // ---- read own-wave state slice x[j] = u[16w+j] (broadcast b128 reads) ----
        float2 x[16];
#pragma unroll
        for (int jj = 0; jj < 8; ++jj)
          *reinterpret_cast<float4*>(&x[2 * jj]) =
              *reinterpret_cast<const float4*>(&ubuf[w][16 * w + 2 * jj]);
        // ---- 16-term complex partial ----
        float pr0 = 0.f, pi0 = 0.f, pr1 = 0.f, pi1 = 0.f;
#pragma unroll
        for (int j = 0; j < 16; j += 2) {
          pr0 = fmaf(Wc[j].x,     x[j].x,     pr0);  pr0 = fmaf(-Wc[j].y,     x[j].y,     pr0);
          pi0 = fmaf(Wc[j].x,     x[j].y,     pi0);  pi0 = fmaf(Wc[j].y,      x[j].x,     pi0);
          pr1 = fmaf(Wc[j + 1].x, x[j + 1].x, pr1);  pr1 = fmaf(-Wc[j + 1].y, x[j + 1].y, pr1);
          pi1 = fmaf(Wc[j + 1].x, x[j + 1].y, pi1);  pi1 = fmaf(Wc[j + 1].y,  x[j + 1].x, pi1);
        }
        pbuf[pb][w][o] = make_float2(pr0 + pr1, pi0 + pi1);
        __syncthreads();
        // ---- combine partials -> k[o] ----
        const float2 q0 = pbuf[pb][0][o], q1 = pbuf[pb][1][o];
        const float2 q2 = pbuf[pb][2][o], q3 = pbuf[pb][3][o];
        const float kr = q0.x + q1.x + q2.x + q3.x + bia;
        const float ki = q0.y + q1.y + q2.y + q3.y;
        const float wsm = (st == 1 || st == 2) ? 2.f : 1.f;
        accr = fmaf(wsm, kr, accr); acci = fmaf(wsm, ki, acci);
        float ur, ui;
        if (st < 3) {
          const float cm = (st < 2) ? 0.5f * h : h;
          ur = fmaf(cm, kr, zr); ui = fmaf(cm, ki, zi);
        } else {
          zr = fmaf(h * (1.f / 6.f), accr, zr);
          zi = fmaf(h * (1.f / 6.f), acci, zi);
          ur = zr; ui = zi;
        }
        ubuf[w][o] = make_float2(ur, ui);   // own-wave; next stage reads it
        pb ^= 1;
      }
    }
  }

  // ---- epilogue (wave 0 has full final state) ----
  if (w == 0) {
    if (isBias) {
      const float g = wave_sum(fmaf(p2w[o], p1b[o], q * zr));
      if (o == 0) ws[WS_GAMMA] = g + p2b[0];
    } else {
      const float sr = wave_sum(q * (zr - lw[o]));
      const float si = wave_sum(q * zi);
      if (o == 0) { ws[WS_S + 2 * m] = sr; ws[WS_S + 2 * m + 1] = si; }
      if (m == 0) {
        const float a = wave_sum(q * lw[o]);
        if (o == 0) ws[WS_ALPHA] = a;
      }
    }
  }
}

// ---------------- fused: x-DFT at tracked rows, *S, inverse over xs ----------------
__global__ void fnde_mid(float* __restrict__ ws) {
  const int b = blockIdx.x >> 4, y = blockIdx.x & 15;
  const int t = threadIdx.x;              // 128
  __shared__ float cr[128], ci[128], tc[128], tsn[128], Sre[kNXI], Sim[kNXI];
  sincosf((float)t * kTheta, &tsn[t], &tc[t]);
  int idx = ((b * 128 + t) * 16 + y) * 2;
  cr[t] = ws[WS_ZY + idx]; ci[t] = ws[WS_ZY + idx + 1];
  __syncthreads();
  if (t < kNXI) {
    int x = (t <= 16) ? t : t + 95;
    float ar = 0.f, ai = 0.f;
    for (int xs = 0; xs < 128; ++xs) {
      int k = (x * xs) & 127;
      float c = tc[k], s = tsn[k];
      ar += cr[xs] * c + ci[xs] * s;
      ai += ci[xs] * c - cr[xs] * s;
    }
    int mm = y * kNXI + t;
    float sr = ws[WS_S + 2 * mm], si = ws[WS_S + 2 * mm + 1];
    Sre[t] = sr * ar - si * ai;
    Sim[t] = sr * ai + si * ar;
  }
  __syncthreads();
  const int xs = t;
  float ar, ai;
  if (y > 0) {
    ar = 0.f; ai = 0.f;
    for (int xj = 0; xj < kNXI; ++xj) {
      int x = (xj <= 16) ? xj : xj + 95;
      int k = (x * xs) & 127;
      float c = tc[k], s = tsn[k];
      ar += Sre[xj] * c - Sim[xj] * s;   // e^{+i}
      ai += Sre[xj] * s + Sim[xj] * c;
    }
  } else {
    ar = Sre[0]; ai = 0.f;               // x-col 0: Hermitian pairs -> real
    for (int xj = 1; xj <= 16; ++xj) {
      int k = (xj * xs) & 127;
      ar += 2.f * (Sre[xj] * tc[k] - Sim[xj] * tsn[k]);
    }
  }
  ws[WS_T + idx] = ar; ws[WS_T + idx + 1] = ai;   // in-place per (b,y) slice
}

// ---------------- inverse stage 2 + epilogue ----------------
__global__ void fnde_final(const float* __restrict__ z, const float* __restrict__ ws,
                           float* __restrict__ out) {
  const int bid = blockIdx.x;             // b*128 + xs
  const int b = bid >> 7, xs = bid & 127;
  const int t = threadIdx.x;              // 128 (ys)
  __shared__ float Tre[16], Tim[16], tc[128], tsn[128];
  sincosf((float)t * kTheta, &tsn[t], &tc[t]);
  if (t < 16) {
    int idx = ((b * 128 + xs) * 16 + t) * 2;
    Tre[t] = ws[WS_T + idx]; Tim[t] = ws[WS_T + idx + 1];
  }
  __syncthreads();
  float acc = Tre[0];
  for (int y = 1; y < 16; ++y) {
    int k = (y * t) & 127;
    acc += 2.f * (Tre[y] * tc[k] - Tim[y] * tsn[k]);   // 2*Re(T * e^{+i})
  }
  float val = ws[WS_ALPHA] * z[b * 16384 + xs * 128 + t] + ws[WS_GAMMA]
            + acc * (1.f / 16384.f);
  out[b * 16384 + xs * 128 + t] = val;
}

}  // namespace

extern "C" void kernel_launch(void* const* d_in, const int* in_sizes, int n_in,
                              void* d_out, int out_size, void* d_ws, size_t ws_size,
                              hipStream_t stream) {
  (void)in_sizes; (void)n_in; (void)out_size; (void)ws_size;
  const float* z   = (const float*)d_in[0];
  const float* lw  = (const float*)d_in[1];
  const float* lb  = (const float*)d_in[2];
  const float* w1  = (const float*)d_in[3];
  const float* w2  = (const float*)d_in[4];
  const float* flb = (const float*)d_in[5];
  const float* p1w = (const float*)d_in[6];
  const float* p1b = (const float*)d_in[7];
  const float* p2w = (const float*)d_in[8];
  const float* p2b = (const float*)d_in[9];
  const float* ts  = (const float*)d_in[10];
  float* ws = (float*)d_ws;
  float* out = (float*)d_out;

  fnde_phase1<<<dim3(kModeBlocks + kFwd1Blocks), dim3(256), 0, stream>>>(
      w1, w2, flb, lw, lb, ts, p1w, p1b, p2w, p2b, z, ws);
  fnde_mid<<<dim3(256), dim3(128), 0, stream>>>(ws);
  fnde_final<<<dim3(2048), dim3(128), 0, stream>>>(z, ws, out);
}

// Round 7
// 94.218 us; speedup vs baseline: 1.6061x; 1.0028x over previous
//
#include <hip/hip_runtime.h>

namespace {

constexpr int kNXI = 33;                    // x rows tracked: 0..16, 112..127
constexpr int kNY = 16;                     // y modes 0..15
constexpr int kNMODE = kNY * kNXI;          // 528 slots (497 active)
constexpr int kModeBlocks = 529;            // 528 mode slots + 1 bias block
constexpr int kFwd1Blocks = 1024;           // 2 rows per block

// ws float offsets
constexpr int WS_ALPHA = 0;
constexpr int WS_GAMMA = 1;
constexpr int WS_S = 4;                                 // s[528] complex
constexpr int WS_ZY = WS_S + kNMODE * 2;                // Zy[16][128][16] complex
constexpr int WS_T = WS_ZY;                             // T aliases Zy

constexpr float kTheta = 0.04908738521234052f;          // 2*pi/128

__device__ __forceinline__ float wave_sum(float v) {
  v += __shfl_xor(v, 1);  v += __shfl_xor(v, 2);  v += __shfl_xor(v, 4);
  v += __shfl_xor(v, 8);  v += __shfl_xor(v, 16); v += __shfl_xor(v, 32);
  return v;
}

// ---------------- phase1: per-mode RK4 (4 waves/mode, i-split) + fwd1 ----------------
// Wave w owns i in [16w,16w+16). ALL 3 layers' W-slices prefetched to VGPRs in the
// prologue (48 float2/lane) so the full ~50MB weight stream is in flight at T=0;
// per-stage exchange via double-buffered LDS partials, one barrier per stage.
__global__ __launch_bounds__(256) void fnde_phase1(
    const float* __restrict__ w1, const float* __restrict__ w2,
    const float* __restrict__ flb, const float* __restrict__ lw,
    const float* __restrict__ lb, const float* __restrict__ ts,
    const float* __restrict__ p1w, const float* __restrict__ p1b,
    const float* __restrict__ p2w, const float* __restrict__ p2b,
    const float* __restrict__ z, float* __restrict__ ws) {
  const int b = blockIdx.x;
  const int t = threadIdx.x;

  if (b >= kModeBlocks) {
    // ---------------- fwd1: forward DFT over ys (2 rows per block) ----------------
    __shared__ float zrow2[2][128], tcf[128], tsnf[128], rre2[2][128], rim2[2][128];
    const int bid = b - kModeBlocks;
    const int r = t >> 7, tt = t & 127;
    const int row = bid * 2 + r;          // row = bb*128 + xs
    const int bb = row >> 7, xs = row & 127;
    if (r == 0) sincosf((float)tt * kTheta, &tsnf[tt], &tcf[tt]);
    zrow2[r][tt] = z[bb * 16384 + xs * 128 + tt];
    __syncthreads();
    int y = tt & 15, part = tt >> 4;      // 8 partial groups
    float sre = 0.f, sim = 0.f;
    for (int j = 0; j < 16; ++j) {
      int ys = (part << 4) + j;
      int k = (y * ys) & 127;
      float zv = zrow2[r][ys];
      sre += zv * tcf[k];
      sim -= zv * tsnf[k];
    }
    rre2[r][tt] = sre; rim2[r][tt] = sim;
    __syncthreads();
    if (tt < 16) {
      float ar = 0.f, ai = 0.f;
      for (int pp = 0; pp < 8; ++pp) { ar += rre2[r][(pp << 4) + tt]; ai += rim2[r][(pp << 4) + tt]; }
      int idx = (row * 16 + tt) * 2;
      ws[WS_ZY + idx] = ar; ws[WS_ZY + idx + 1] = ai;
    }
    return;
  }

  // ---------------- mode / bias blocks ----------------
  const int w = t >> 6, o = t & 63;
  const bool isBias = (b == kModeBlocks - 1);

  int xi = 0, y = 0, m = 0;
  if (!isBias) {
    const int xcd = b & 7, k = b >> 3;     // XCD affinity: 16 y's of one xi share an XCD
    if (k < 64) { xi = xcd * 4 + (k >> 4); y = k & 15; }
    else        { xi = 32;                 y = xcd * 2 + (k - 64); }
    m = y * kNXI + xi;
    const bool inactive = (y == 0) ? (xi > 16) : (xi == 16);
    if (inactive) {
      if (t == 0) { ws[WS_S + 2 * m] = 0.f; ws[WS_S + 2 * m + 1] = 0.f; }
      return;
    }
  }

  __shared__ float2 ubuf[4][64];          // per-wave full-state copies
  __shared__ float2 pbuf[2][4][64];       // double-buffered partials

  // ---- PROLOGUE: issue all 3 layers' weight loads (except y==0 Hermitian) ----
  const bool pfAll = isBias || (y >= 1);
  float2 Wall[48];
  if (pfAll) {
    if (isBias) {
      const float* lanep = w1 + o * 512;
#pragma unroll
      for (int l = 0; l < 3; ++l)
#pragma unroll
        for (int j = 0; j < 16; ++j)
          Wall[l * 16 + j] =
              make_float2(lanep[(size_t)(l * 64 + 16 * w + j) * 32768], 0.f);
    } else {
      const float* lanep = ((xi <= 15) ? (w1 + (xi * 16 + y) * 2)
                                       : (w2 + ((xi - 17) * 16 + y) * 2)) + o * 512;
#pragma unroll
      for (int l = 0; l < 3; ++l)
#pragma unroll
        for (int j = 0; j < 16; ++j)
          Wall[l * 16 + j] = *reinterpret_cast<const float2*>(
              lanep + (size_t)(l * 64 + 16 * w + j) * 32768);
    }
  }

  const float t0 = ts[0], t1 = ts[1], t2 = ts[2], t3 = ts[3], t4 = ts[4];
  const float h0 = t1 - t0, h1 = t2 - t1, h2 = t3 - t2, h3 = t4 - t3;

  float q = 0.f;
  if (w == 0) {
    for (int p = 0; p < 64; ++p) q = fmaf(p2w[p], p1w[p * 64 + o], q);
  }

  float zr = isBias ? lb[o] : lw[o], zi = 0.f;
  ubuf[w][o] = make_float2(zr, zi);       // own-wave write; own-wave reads below

  int pb = 0;

#pragma unroll
  for (int l = 0; l < 3; ++l) {
    float2 Wc[16];
    if (pfAll) {
#pragma unroll
      for (int j = 0; j < 16; ++j) Wc[j] = Wall[l * 16 + j];
    } else {
      // y==0: Hermitian combine of w1 and conj(w2 partner), per layer (L2-served)
      const bool hasA = (xi <= 15);
      const float* lanepA = w1 + xi * 32 + o * 512;
      const float* lanepB = (xi >= 1) ? (w2 + (16 - xi) * 32 + o * 512)
                                      : (w1 + o * 512);
#pragma unroll
      for (int j = 0; j < 16; ++j) {
        const size_t ioff = (size_t)(l * 64 + 16 * w + j) * 32768;
        const float2 a = hasA ? *reinterpret_cast<const float2*>(lanepA + ioff)
                              : make_float2(0.f, 0.f);
        const float2 bb2 = *reinterpret_cast<const float2*>(lanepB + ioff);
        Wc[j] = make_float2(0.5f * (a.x + bb2.x), 0.5f * (a.y - bb2.y));
      }
    }
    const float bia = isBias ? flb[l * 64 + o] : 0.f;

    for (int step = 0; step < 4; ++step) {
      const float h = (step == 0) ? h0 : (step == 1) ? h1 : (step == 2) ? h2 : h3;
      float accr = 0.f, acci = 0.f;
      for (int st = 0; st < 4; ++st) {
        // ---- read own-wave state slice x[j] = u[16w+j] (b128 reads) ----
        float2 x[16];
#pragma unroll
        for (int jj = 0; jj < 8; ++jj)
          *reinterpret_cast<float4*>(&x[2 * jj]) =
              *reinterpret_cast<const float4*>(&ubuf[w][16 * w + 2 * jj]);
        // ---- 16-term complex partial ----
        float pr0 = 0.f, pi0 = 0.f, pr1 = 0.f, pi1 = 0.f;
#pragma unroll
        for (int j = 0; j < 16; j += 2) {
          pr0 = fmaf(Wc[j].x,     x[j].x,     pr0);  pr0 = fmaf(-Wc[j].y,     x[j].y,     pr0);
          pi0 = fmaf(Wc[j].x,     x[j].y,     pi0);  pi0 = fmaf(Wc[j].y,      x[j].x,     pi0);
          pr1 = fmaf(Wc[j + 1].x, x[j + 1].x, pr1);  pr1 = fmaf(-Wc[j + 1].y, x[j + 1].y, pr1);
          pi1 = fmaf(Wc[j + 1].x, x[j + 1].y, pi1);  pi1 = fmaf(Wc[j + 1].y,  x[j + 1].x, pi1);
        }
        pbuf[pb][w][o] = make_float2(pr0 + pr1, pi0 + pi1);
        __syncthreads();
        // ---- combine partials -> k[o] ----
        const float2 q0 = pbuf[pb][0][o], q1 = pbuf[pb][1][o];
        const float2 q2 = pbuf[pb][2][o], q3 = pbuf[pb][3][o];
        const float kr = q0.x + q1.x + q2.x + q3.x + bia;
        const float ki = q0.y + q1.y + q2.y + q3.y;
        const float wsm = (st == 1 || st == 2) ? 2.f : 1.f;
        accr = fmaf(wsm, kr, accr); acci = fmaf(wsm, ki, acci);
        float ur, ui;
        if (st < 3) {
          const float cm = (st < 2) ? 0.5f * h : h;
          ur = fmaf(cm, kr, zr); ui = fmaf(cm, ki, zi);
        } else {
          zr = fmaf(h * (1.f / 6.f), accr, zr);
          zi = fmaf(h * (1.f / 6.f), acci, zi);
          ur = zr; ui = zi;
        }
        ubuf[w][o] = make_float2(ur, ui);   // own-wave; next stage reads it
        pb ^= 1;
      }
    }
  }

  // ---- epilogue (wave 0 has full final state) ----
  if (w == 0) {
    if (isBias) {
      const float g = wave_sum(fmaf(p2w[o], p1b[o], q * zr));
      if (o == 0) ws[WS_GAMMA] = g + p2b[0];
    } else {
      const float sr = wave_sum(q * (zr - lw[o]));
      const float si = wave_sum(q * zi);
      if (o == 0) { ws[WS_S + 2 * m] = sr; ws[WS_S + 2 * m + 1] = si; }
      if (m == 0) {
        const float a = wave_sum(q * lw[o]);
        if (o == 0) ws[WS_ALPHA] = a;
      }
    }
  }
}

// ---------------- fused: x-DFT at tracked rows, *S, inverse over xs ----------------
__global__ void fnde_mid(float* __restrict__ ws) {
  const int b = blockIdx.x >> 4, y = blockIdx.x & 15;
  const int t = threadIdx.x;              // 128
  __shared__ float cr[128], ci[128], tc[128], tsn[128], Sre[kNXI], Sim[kNXI];
  sincosf((float)t * kTheta, &tsn[t], &tc[t]);
  int idx = ((b * 128 + t) * 16 + y) * 2;
  cr[t] = ws[WS_ZY + idx]; ci[t] = ws[WS_ZY + idx + 1];
  __syncthreads();
  if (t < kNXI) {
    int x = (t <= 16) ? t : t + 95;
    float ar = 0.f, ai = 0.f;
    for (int xs = 0; xs < 128; ++xs) {
      int k = (x * xs) & 127;
      float c = tc[k], s = tsn[k];
      ar += cr[xs] * c + ci[xs] * s;
      ai += ci[xs] * c - cr[xs] * s;
    }
    int mm = y * kNXI + t;
    float sr = ws[WS_S + 2 * mm], si = ws[WS_S + 2 * mm + 1];
    Sre[t] = sr * ar - si * ai;
    Sim[t] = sr * ai + si * ar;
  }
  __syncthreads();
  const int xs = t;
  float ar, ai;
  if (y > 0) {
    ar = 0.f; ai = 0.f;
    for (int xj = 0; xj < kNXI; ++xj) {
      int x = (xj <= 16) ? xj : xj + 95;
      int k = (x * xs) & 127;
      float c = tc[k], s = tsn[k];
      ar += Sre[xj] * c - Sim[xj] * s;   // e^{+i}
      ai += Sre[xj] * s + Sim[xj] * c;
    }
  } else {
    ar = Sre[0]; ai = 0.f;               // x-col 0: Hermitian pairs -> real
    for (int xj = 1; xj <= 16; ++xj) {
      int k = (xj * xs) & 127;
      ar += 2.f * (Sre[xj] * tc[k] - Sim[xj] * tsn[k]);
    }
  }
  ws[WS_T + idx] = ar; ws[WS_T + idx + 1] = ai;   // in-place per (b,y) slice
}

// ---------------- inverse stage 2 + epilogue ----------------
__global__ void fnde_final(const float* __restrict__ z, const float* __restrict__ ws,
                           float* __restrict__ out) {
  const int bid = blockIdx.x;             // b*128 + xs
  const int b = bid >> 7, xs = bid & 127;
  const int t = threadIdx.x;              // 128 (ys)
  __shared__ float Tre[16], Tim[16], tc[128], tsn[128];
  sincosf((float)t * kTheta, &tsn[t], &tc[t]);
  if (t < 16) {
    int idx = ((b * 128 + xs) * 16 + t) * 2;
    Tre[t] = ws[WS_T + idx]; Tim[t] = ws[WS_T + idx + 1];
  }
  __syncthreads();
  float acc = Tre[0];
  for (int y = 1; y < 16; ++y) {
    int k = (y * t) & 127;
    acc += 2.f * (Tre[y] * tc[k] - Tim[y] * tsn[k]);   // 2*Re(T * e^{+i})
  }
  float val = ws[WS_ALPHA] * z[b * 16384 + xs * 128 + t] + ws[WS_GAMMA]
            + acc * (1.f / 16384.f);
  out[b * 16384 + xs * 128 + t] = val;
}

}  // namespace

extern "C" void kernel_launch(void* const* d_in, const int* in_sizes, int n_in,
                              void* d_out, int out_size, void* d_ws, size_t ws_size,
                              hipStream_t stream) {
  (void)in_sizes; (void)n_in; (void)out_size; (void)ws_size;
  const float* z   = (const float*)d_in[0];
  const float* lw  = (const float*)d_in[1];
  const float* lb  = (const float*)d_in[2];
  const float* w1  = (const float*)d_in[3];
  const float* w2  = (const float*)d_in[4];
  const float* flb = (const float*)d_in[5];
  const float* p1w = (const float*)d_in[6];
  const float* p1b = (const float*)d_in[7];
  const float* p2w = (const float*)d_in[8];
  const float* p2b = (const float*)d_in[9];
  const float* ts  = (const float*)d_in[10];
  float* ws = (float*)d_ws;
  float* out = (float*)d_out;

  fnde_phase1<<<dim3(kModeBlocks + kFwd1Blocks), dim3(256), 0, stream>>>(
      w1, w2, flb, lw, lb, ts, p1w, p1b, p2w, p2b, z, ws);
  fnde_mid<<<dim3(256), dim3(128), 0, stream>>>(ws);
  fnde_final<<<dim3(2048), dim3(128), 0, stream>>>(z, ws, out);
}